// Round 10
// baseline (3244.125 us; speedup 1.0000x reference)
//
#include <hip/hip_runtime.h>
#include <hip/hip_fp16.h>
#include <stdint.h>

#define TT 1024
#define BB 64
#define DHH 256
#define HH 512
#define G3 1536
#define CHK 256   // f16 per (g,jsl) exchange chunk: [16 batches][16 j] — ONE constant for store/poll/reader
#define KF 6      // bounded fast-poll attempts (L2 path); fallback to MALL poll — hang-proof

typedef _Float16 f16;
typedef _Float16 f16x4 __attribute__((ext_vector_type(4)));
typedef _Float16 f16x8 __attribute__((ext_vector_type(8)));
typedef float f32x4 __attribute__((ext_vector_type(4)));
typedef unsigned long long u64;

__device__ __forceinline__ float sigm(float x){ return 1.0f/(1.0f+__expf(-x)); }
__device__ __forceinline__ float tanh_f(float x){ return 2.0f/(1.0f+__expf(-2.0f*x)) - 1.0f; }

// ---------------- prep: f32->f16 weights, folded bias ----------------
__global__ void k_prep(const float* __restrict__ wih, const float* __restrict__ whh,
                       const float* __restrict__ bih, const float* __restrict__ bhh,
                       f16* __restrict__ wih_h, f16* __restrict__ whh_h, float* __restrict__ biasf){
  int i = blockIdx.x*256 + threadIdx.x;
  if (i < G3*HH){ wih_h[i] = (f16)wih[i]; whh_h[i] = (f16)whh[i]; }
  if (i < G3) biasf[i] = bih[i] + (i < 2*HH ? bhh[i] : 0.0f);
}

// ---------------- build x = concat(s, p.sum(axis=2)) as f16 [T*B][512] ----------------
__global__ void k_buildx(const float* __restrict__ s, const float* __restrict__ p, f16* __restrict__ x){
  int m = blockIdx.x;             // m = t*64 + b
  int t = m >> 6, b = m & 63;
  int l = threadIdx.x;            // 0..63 -> 4 floats each
  const float4* s4 = reinterpret_cast<const float4*>(s + ((size_t)b*TT + t)*DHH);
  const float4* p4 = reinterpret_cast<const float4*>(p + ((size_t)b*TT + t)*8*DHH);
  float4 sv = s4[l];
  float4 a  = p4[l];
#pragma unroll
  for (int k=1;k<8;k++){ float4 v = p4[k*64 + l]; a.x+=v.x; a.y+=v.y; a.z+=v.z; a.w+=v.w; }
  f16* xr = x + (size_t)m*HH;
  f16x4 hs = { (f16)sv.x,(f16)sv.y,(f16)sv.z,(f16)sv.w };
  f16x4 hp = { (f16)a.x,(f16)a.y,(f16)a.z,(f16)a.w };
  *reinterpret_cast<f16x4*>(xr + l*4)       = hs;
  *reinterpret_cast<f16x4*>(xr + 256 + l*4) = hp;
}

// ---------------- gi GEMM (round-8 validated layout) ----------------
// gi[((t*16+ksl)*4+g)*16 + b'][96] f16, 96 = gate*32 + j'
#define LDAP 72
__global__ __launch_bounds__(256) void k_gemm(const f16* __restrict__ x, const f16* __restrict__ w,
                       const float* __restrict__ biasf, f16* __restrict__ gi){
  __shared__ f16 lA[128*LDAP];
  __shared__ f16 lB[128*LDAP];
  int by = blockIdx.x;           // wrow tile (12)
  int bx = blockIdx.y;           // xrow tile (512)
  int tid = threadIdx.x, l = tid & 63, wv = tid >> 6;
  int wm = wv >> 1, wn = wv & 1;

  f32x4 acc[4][4];
#pragma unroll
  for (int i=0;i<4;i++)
#pragma unroll
    for (int j=0;j<4;j++) acc[i][j] = (f32x4){0.f,0.f,0.f,0.f};

  for (int kt = 0; kt < 8; ++kt){
#pragma unroll
    for (int r = 0; r < 4; ++r){
      int c = tid + 256*r;
      int row = c >> 3, o = c & 7;
      f16x8 va = *reinterpret_cast<const f16x8*>(w + (size_t)(by*128+row)*HH + kt*64 + o*8);
      f16x8 vb = *reinterpret_cast<const f16x8*>(x + (size_t)(bx*128+row)*HH + kt*64 + o*8);
      *reinterpret_cast<f16x8*>(&lA[row*LDAP + o*8]) = va;
      *reinterpret_cast<f16x8*>(&lB[row*LDAP + o*8]) = vb;
    }
    __syncthreads();
#pragma unroll
    for (int kk = 0; kk < 2; ++kk){
      f16x8 aF[4], bF[4];
#pragma unroll
      for (int mi=0;mi<4;mi++)
        aF[mi] = *reinterpret_cast<const f16x8*>(&lA[(wm*64+mi*16+(l&15))*LDAP + kk*32 + (l>>4)*8]);
#pragma unroll
      for (int ni=0;ni<4;ni++)
        bF[ni] = *reinterpret_cast<const f16x8*>(&lB[(wn*64+ni*16+(l&15))*LDAP + kk*32 + (l>>4)*8]);
#pragma unroll
      for (int mi=0;mi<4;mi++)
#pragma unroll
        for (int ni=0;ni<4;ni++)
          acc[mi][ni] = __builtin_amdgcn_mfma_f32_16x16x32_f16(aF[mi], bF[ni], acc[mi][ni], 0,0,0);
    }
    __syncthreads();
  }
#pragma unroll
  for (int mi=0;mi<4;mi++){
    int wrow0 = by*128 + wm*64 + mi*16 + (l>>4)*4;
    float4 bv = *reinterpret_cast<const float4*>(biasf + wrow0);
    int gate = wrow0 >> 9, j = wrow0 & 511, ksl = j >> 5, rp = gate*32 + (j&31);
#pragma unroll
    for (int ni=0;ni<4;ni++){
      int xrow = bx*128 + wn*64 + ni*16 + (l&15);
      int t = xrow >> 6, g = (xrow>>4)&3, bp = xrow & 15;
      size_t dst = ((((size_t)t*16 + ksl)*4 + g)*16 + bp)*96 + rp;
      union { u64 u; f16x4 h; } cv;
      cv.h = (f16x4){ (f16)(acc[mi][ni][0]+bv.x), (f16)(acc[mi][ni][1]+bv.y),
                      (f16)(acc[mi][ni][2]+bv.z), (f16)(acc[mi][ni][3]+bv.w) };
      *reinterpret_cast<u64*>(gi + dst) = cv.u;
    }
  }
}

// ---------------- persistent GRU scan: round-8 base + hang-proof XCD-local fast path ----------------
// 64 WGs x 256 thr; WGs with (bid&7)>=4 exit. Group g = bid&7 in {0..3} (16 batches): its 8 WGs
// share bid%8 -> one XCD under measured RR dispatch. Wave w of WG c owns jsl = c*4+w (48 W rows
// in AGPRs). DUAL-STORE producer: sc0 store (write-through to XCD L2) to hfast + relaxed agent
// atomic (MALL, round-7/8-proven) to hmall. Consumer: <=KF sc0 poll attempts on hfast (L2 RT);
// on exhaustion, fall back to the proven MALL poll on hmall — NO branch can livelock, correctness
// never depends on WG->XCD mapping (G16). Poll-the-data: buffers poisoned 0xFF; finite h never
// yields f16 0xFFFF; each u64 is one store (all-or-nothing).
__global__ __launch_bounds__(256, 1) void k_scan(const f16* __restrict__ whh_h, const f16* __restrict__ gi,
                      const float* __restrict__ bhh, f16* __restrict__ hfast, f16* __restrict__ hmall){
  __shared__ f16 hbF[2][16][64][8];                 // [parity][kt][frag-lane][8 f16] = 32 KB
  const int bid = blockIdx.x;                       // 0..63
  if ((bid & 7) >= 4) return;                       // keep residues 0..3 (XCDs 0..3 under RR)
  const int g = bid & 7, c = bid >> 3;              // group 0..3, wg-in-group 0..7
  const int tid = threadIdx.x;
  const int w = tid >> 6, l = tid & 63;
  const int lm = l & 15, lh = l >> 4;
  const int jsl = c*4 + w;                          // 0..31: this wave's 16-j slice

  // persistent A-fragments: aW[gate][kt], W row = gate*512 + jsl*16 + lm, k = kt*32 + lh*8
  f16x8 aW[3][16];
#pragma unroll
  for (int gate = 0; gate < 3; ++gate){
    const f16* wr = whh_h + ((size_t)gate*512 + jsl*16 + lm)*HH + lh*8;
#pragma unroll
    for (int kt = 0; kt < 16; ++kt)
      aW[gate][kt] = *reinterpret_cast<const f16x8*>(wr + kt*32);
  }
#pragma unroll
  for (int gate = 0; gate < 3; ++gate)
#pragma unroll
    for (int kt = 0; kt < 16; ++kt)
      asm volatile("" : "+a"(aW[gate][kt]));        // pin W in AGPRs (no remat, no spill)

  float4 bnv = *reinterpret_cast<const float4*>(bhh + 2*HH + jsl*16 + lh*4);
  float bna[4] = {bnv.x, bnv.y, bnv.z, bnv.w};
  const int ksl2 = jsl >> 1, jo = (jsl & 1)*16 + lh*4;     // gi addressing

  union U64H { u64 u; f16x4 h; };
  U64H cA[3], cB[3], cC[3], ho, hn;
  ho.u = 0ull;

  // producer chunk offset (all 64 lanes store distinct u64): lm*16 + lh*4
  const size_t pofs = (size_t)lm*16 + lh*4;
  auto publish = [&](int t, u64 v){
    const size_t cbase = (((size_t)t*4 + g)*32 + jsl)*CHK + pofs;
    f16* fd = hfast + cbase;
    asm volatile("global_store_dwordx2 %0, %1, off sc0" :: "v"(fd), "v"(v) : "memory");
    __hip_atomic_store(reinterpret_cast<u64*>(hmall + cbase), v,
                       __ATOMIC_RELAXED, __HIP_MEMORY_SCOPE_AGENT);
  };

  // ---- t = 0 peel: h_{-1}=0, no poll; prefetch gi(1)->cB, gi(2)->cC ----
  {
    const f16* g0 = gi + ((((size_t)0*16 + ksl2)*4 + g)*16 + lm)*96;
    cA[0].u = *reinterpret_cast<const u64*>(g0 + jo);
    cA[1].u = *reinterpret_cast<const u64*>(g0 + 32 + jo);
    cA[2].u = *reinterpret_cast<const u64*>(g0 + 64 + jo);
    const f16* g1 = gi + ((((size_t)1*16 + ksl2)*4 + g)*16 + lm)*96;
    cB[0].u = *reinterpret_cast<const u64*>(g1 + jo);
    cB[1].u = *reinterpret_cast<const u64*>(g1 + 32 + jo);
    cB[2].u = *reinterpret_cast<const u64*>(g1 + 64 + jo);
    const f16* g2 = gi + ((((size_t)2*16 + ksl2)*4 + g)*16 + lm)*96;
    cC[0].u = *reinterpret_cast<const u64*>(g2 + jo);
    cC[1].u = *reinterpret_cast<const u64*>(g2 + 32 + jo);
    cC[2].u = *reinterpret_cast<const u64*>(g2 + 64 + jo);
#pragma unroll
    for (int r = 0; r < 4; ++r){
      float rg = sigm((float)cA[0].h[r]);
      float zg = sigm((float)cA[1].h[r]);
      float ng = tanh_f((float)cA[2].h[r] + rg*bna[r]);
      hn.h[r] = (f16)((1.0f - zg)*ng);
    }
    ho.u = hn.u;
    publish(0, hn.u);
  }

  // BODY(T): fast sc0 poll (<=KF) else MALL poll -> stage B-frag LDS; barrier; gi(T+2); MFMA; gates; publish.
#define BODY(T, CUR, NXT2)                                                                           \
  {                                                                                                  \
    const int t_ = (T);                                                                              \
    const int par = t_ & 1;                                                                          \
    const size_t pollbase = (((size_t)(t_-1)*4 + g)*32 + w*8)*CHK;   /* chunks w*8..w*8+7 */          \
    u64 qq[8];                                                                                       \
    int got = 0;                                                                                     \
    {                                                                                                \
      const char* fb = reinterpret_cast<const char*>(hfast + pollbase) + (size_t)l*8;                \
      for (int att = 0; att < KF && !got; ++att){                                                    \
        u64 ff0,ff1,ff2,ff3,ff4,ff5,ff6,ff7;                                                         \
        asm volatile(                                                                                \
          "global_load_dwordx2 %0, %8, off sc0\n\t"                                                  \
          "global_load_dwordx2 %1, %8, off offset:512 sc0\n\t"                                       \
          "global_load_dwordx2 %2, %8, off offset:1024 sc0\n\t"                                      \
          "global_load_dwordx2 %3, %8, off offset:1536 sc0\n\t"                                      \
          "global_load_dwordx2 %4, %8, off offset:2048 sc0\n\t"                                      \
          "global_load_dwordx2 %5, %8, off offset:2560 sc0\n\t"                                      \
          "global_load_dwordx2 %6, %8, off offset:3072 sc0\n\t"                                      \
          "global_load_dwordx2 %7, %8, off offset:3584 sc0\n\t"                                      \
          "s_waitcnt vmcnt(0)"                                                                       \
          : "=&v"(ff0),"=&v"(ff1),"=&v"(ff2),"=&v"(ff3),                                             \
            "=&v"(ff4),"=&v"(ff5),"=&v"(ff6),"=&v"(ff7)                                              \
          : "v"(fb) : "memory");                                                                     \
        int ok = (int)((unsigned)ff0 != 0xFFFFFFFFu) & (int)((unsigned)ff1 != 0xFFFFFFFFu)           \
               & (int)((unsigned)ff2 != 0xFFFFFFFFu) & (int)((unsigned)ff3 != 0xFFFFFFFFu)           \
               & (int)((unsigned)ff4 != 0xFFFFFFFFu) & (int)((unsigned)ff5 != 0xFFFFFFFFu)           \
               & (int)((unsigned)ff6 != 0xFFFFFFFFu) & (int)((unsigned)ff7 != 0xFFFFFFFFu);          \
        got = __all(ok);                                                                             \
        if (got){ qq[0]=ff0; qq[1]=ff1; qq[2]=ff2; qq[3]=ff3;                                        \
                  qq[4]=ff4; qq[5]=ff5; qq[6]=ff6; qq[7]=ff7; }                                      \
      }                                                                                              \
    }                                                                                                \
    if (!got){                                                                                       \
      const u64* hsrc = reinterpret_cast<const u64*>(hmall + pollbase) + l;                          \
      int ok;                                                                                        \
      do {                                                                                           \
        ok = 1;                                                                                      \
        _Pragma("unroll")                                                                            \
        for (int q = 0; q < 8; ++q){                                                                 \
          qq[q] = __hip_atomic_load(hsrc + (size_t)q*(CHK/4), __ATOMIC_RELAXED, __HIP_MEMORY_SCOPE_AGENT); \
          ok &= ((unsigned)qq[q] != 0xFFFFFFFFu);                                                    \
        }                                                                                            \
      } while (!__all(ok));                                                                          \
    }                                                                                                \
    _Pragma("unroll")                                                                                \
    for (int q = 0; q < 8; ++q){                                                                     \
      const int jj  = w*8 + q;                                                                       \
      const int ktq = jj >> 1;                                                                       \
      const int lhq = (jj & 1)*2 + ((l&3)>>1);                                                       \
      *reinterpret_cast<u64*>(&hbF[par][ktq][(l>>2) + 16*lhq][(l&1)*4]) = qq[q];                     \
    }                                                                                                \
    __syncthreads();                                                                                 \
    {   /* gi(t+2) prefetch, consumed 2 steps later */                                               \
      const int tn_ = (t_+2 < TT) ? t_+2 : TT-1;                                                     \
      const f16* gn = gi + ((((size_t)tn_*16 + ksl2)*4 + g)*16 + lm)*96;                             \
      NXT2[0].u = *reinterpret_cast<const u64*>(gn + jo);                                            \
      NXT2[1].u = *reinterpret_cast<const u64*>(gn + 32 + jo);                                       \
      NXT2[2].u = *reinterpret_cast<const u64*>(gn + 64 + jo);                                       \
    }                                                                                                \
    f32x4 aR = (f32x4){0.f,0.f,0.f,0.f};                                                             \
    f32x4 aZ = (f32x4){0.f,0.f,0.f,0.f};                                                             \
    f32x4 aN = (f32x4){0.f,0.f,0.f,0.f};                                                             \
    _Pragma("unroll")                                                                                \
    for (int kt = 0; kt < 16; ++kt){                                                                 \
      f16x8 bF = *reinterpret_cast<const f16x8*>(&hbF[par][kt][l][0]);                               \
      aR = __builtin_amdgcn_mfma_f32_16x16x32_f16(aW[0][kt], bF, aR, 0,0,0);                         \
      aZ = __builtin_amdgcn_mfma_f32_16x16x32_f16(aW[1][kt], bF, aZ, 0,0,0);                         \
      aN = __builtin_amdgcn_mfma_f32_16x16x32_f16(aW[2][kt], bF, aN, 0,0,0);                         \
    }                                                                                                \
    _Pragma("unroll")                                                                                \
    for (int r = 0; r < 4; ++r){                                                                     \
      float rg = sigm((float)CUR[0].h[r] + aR[r]);                                                   \
      float zg = sigm((float)CUR[1].h[r] + aZ[r]);                                                   \
      float ng = tanh_f((float)CUR[2].h[r] + rg*(aN[r] + bna[r]));                                   \
      hn.h[r] = (f16)((1.0f - zg)*ng + zg*(float)ho.h[r]);                                           \
    }                                                                                                \
    ho.u = hn.u;                                                                                     \
    publish(t_, hn.u);                                                                               \
  }

  // t = 1..1023 in 341 triples, 3-buffer gi rotation
  for (int t = 1; t < TT; t += 3){
    BODY(t,   cB, cA)
    BODY(t+1, cC, cB)
    BODY(t+2, cA, cC)
  }
#undef BODY
}

// ---------------- rewards = sigmoid(h @ W_t + b_t) (chunked hmall layout, stride CHK) ----------------
__global__ void k_reward(const f16* __restrict__ hh, const float* __restrict__ wt,
                         const float* __restrict__ bt, float* __restrict__ out){
  int wv = threadIdx.x >> 6, l = threadIdx.x & 63;
  int idx = blockIdx.x*4 + wv;          // idx = b*1024 + t (output order [B][T])
  int b = idx >> 10, t = idx & 1023;
  int g = b >> 4, bl = b & 15;
  const f16* hr = hh + (((size_t)t*4 + g)*32 + (l >> 1))*CHK + bl*16 + (l & 1)*8;
  f16x8 hv = *reinterpret_cast<const f16x8*>(hr);
  float4 w0 = *reinterpret_cast<const float4*>(wt + l*8);
  float4 w1 = *reinterpret_cast<const float4*>(wt + l*8 + 4);
  float sum = (float)hv[0]*w0.x + (float)hv[1]*w0.y + (float)hv[2]*w0.z + (float)hv[3]*w0.w
            + (float)hv[4]*w1.x + (float)hv[5]*w1.y + (float)hv[6]*w1.z + (float)hv[7]*w1.w;
#pragma unroll
  for (int m=32;m>=1;m>>=1) sum += __shfl_xor(sum, m);
  if (l==0) out[idx] = sigm(sum + bt[0]);
}

extern "C" void kernel_launch(void* const* d_in, const int* in_sizes, int n_in,
                              void* d_out, int out_size, void* d_ws, size_t ws_size,
                              hipStream_t stream) {
  const float* s   = (const float*)d_in[0];
  const float* p   = (const float*)d_in[1];
  const float* wih = (const float*)d_in[2];
  const float* whh = (const float*)d_in[3];
  const float* bih = (const float*)d_in[4];
  const float* bhh = (const float*)d_in[5];
  const float* wt  = (const float*)d_in[6];
  const float* bt  = (const float*)d_in[7];
  float* out = (float*)d_out;

  char* ws = (char*)d_ws;
  size_t o = 0;
  auto take = [&](size_t bytes)->char*{ char* r = ws + o; o = (o + bytes + 255) & ~(size_t)255; return r; };
  f16*      x_h   = (f16*)   take((size_t)TT*BB*HH*2);       // 67 MB; reused as hfast after k_gemm
  f16*      wih_h = (f16*)   take((size_t)G3*HH*2);
  f16*      whh_h = (f16*)   take((size_t)G3*HH*2);
  float*    biasf = (float*) take((size_t)G3*4);
  f16*      gi_s  = (f16*)   take((size_t)TT*BB*G3*2);       // 201 MB
  f16*      hmall = (f16*)   take((size_t)TT*BB*HH*2);       // 67 MB, MALL buffer (always complete)
  f16*      hfast = x_h;                                     // alias: x dead after k_gemm
  (void)ws_size; (void)in_sizes; (void)n_in; (void)out_size;

  hipMemsetAsync(hmall, 0xFF, (size_t)TT*BB*HH*2, stream);   // poison: poll-the-data sentinel
  k_prep  <<<3072, 256, 0, stream>>>(wih, whh, bih, bhh, wih_h, whh_h, biasf);
  k_buildx<<<TT*BB, 64, 0, stream>>>(s, p, x_h);
  k_gemm  <<<dim3(12, 512), 256, 0, stream>>>(x_h, wih_h, biasf, gi_s);
  hipMemsetAsync(hfast, 0xFF, (size_t)TT*BB*HH*2, stream);   // poison fast buffer (after gemm reads x)
  k_scan  <<<64, 256, 0, stream>>>(whh_h, gi_s, bhh, hfast, hmall);
  k_reward<<<TT*BB/4, 256, 0, stream>>>(hmall, wt, bt, out);
}